// Round 1
// baseline (222.414 us; speedup 1.0000x reference)
//
#include <hip/hip_runtime.h>

// Fused DressedQuantumNet:
//   pre = in[65536,512] @ W_pre.T[512,4] + b_pre          (memory-bound: 134 MB read)
//   q_in = tanh(pre) * pi/2
//   q_out = 4-qubit circuit (16 real amplitudes, registers)
//   out = q_out @ W_post.T[4,200] + b_post                (52 MB write)
// Single kernel, block=256 (4 waves), each wave owns 16 samples, grid = B/64.

#define BLOCK 256
#define WS 16            // samples per wave
#define SPB 64           // samples per block (4 waves * WS)

__device__ __forceinline__ float wred64(float v) {
  v += __shfl_xor(v, 32, 64);
  v += __shfl_xor(v, 16, 64);
  v += __shfl_xor(v, 8, 64);
  v += __shfl_xor(v, 4, 64);
  v += __shfl_xor(v, 2, 64);
  v += __shfl_xor(v, 1, 64);
  return v;
}

// RY(theta) on qubit Q of a 16-amp state; amp index i: qubit q lives at bit (3-q).
template<int Q>
__device__ __forceinline__ void apply_ry(float (&st)[16], float c, float s) {
  constexpr int pos = 3 - Q;
  #pragma unroll
  for (int i = 0; i < 16; ++i) {
    if (((i >> pos) & 1) == 0) {
      const int j = i | (1 << pos);
      const float a = st[i], b = st[j];
      st[i] = c * a - s * b;   // new0 = c*s0 - s*s1
      st[j] = s * a + c * b;   // new1 = s*s0 + c*s1
    }
  }
}

// CNOT(ctrl C, target T): swap target bit where control bit == 1. Pure register renames.
template<int C, int T>
__device__ __forceinline__ void cnot(float (&st)[16]) {
  constexpr int pc = 3 - C, pt = 3 - T;
  #pragma unroll
  for (int i = 0; i < 16; ++i) {
    if ((((i >> pc) & 1) == 1) && (((i >> pt) & 1) == 0)) {
      const int j = i | (1 << pt);
      const float t = st[i]; st[i] = st[j]; st[j] = t;
    }
  }
}

__global__ __launch_bounds__(BLOCK, 4) void dqnet_kernel(
    const float* __restrict__ in, const float* __restrict__ Wpre,
    const float* __restrict__ bpre, const float* __restrict__ qp,
    const float* __restrict__ Wpost, const float* __restrict__ bpost,
    float* __restrict__ out) {
  __shared__ float s_wpost[200 * 4];   // [j][q], float4 rows
  __shared__ float s_bpost[200];
  __shared__ float s_c[24];            // cos(qw[k,q]/2)
  __shared__ float s_sn[24];           // sin(qw[k,q]/2)
  __shared__ float s_qout[SPB * 4];    // [sample_local][q]

  const int tid = threadIdx.x;
  const int lane = tid & 63;
  const int wave = tid >> 6;

  // ---- setup: stage W_post/b_post and shared-layer sincos into LDS ----
  if (tid < 200) {
    ((float4*)s_wpost)[tid] = ((const float4*)Wpost)[tid];
    s_bpost[tid] = bpost[tid];
  } else if (tid < 224) {
    const int k = tid - 200;
    const float a = qp[k] * 0.5f;
    s_c[k] = __cosf(a);
    s_sn[k] = __sinf(a);
  }

  // Per-lane W_pre fragment: lane covers features [lane*4, lane*4+4) and +256.
  float4 wa[4], wb[4];
  #pragma unroll
  for (int q = 0; q < 4; ++q) {
    wa[q] = *(const float4*)(Wpre + q * 512 + lane * 4);
    wb[q] = *(const float4*)(Wpre + q * 512 + 256 + lane * 4);
  }

  // ---- Phase A: pre-GEMV. Wave reads one full row/sample, coalesced. ----
  const int tile = blockIdx.x * SPB + wave * WS;     // first sample of this wave
  const float* rb = in + (size_t)tile * 512 + lane * 4;

  float r0 = 0.f, r1 = 0.f, r2 = 0.f, r3 = 0.f;      // lane s keeps sample s
  float4 xa = *(const float4*)rb;
  float4 xb = *(const float4*)(rb + 256);
  #pragma unroll 4
  for (int s2 = 0; s2 < WS; ++s2) {
    float4 na = xa, nb = xb;
    if (s2 + 1 < WS) {   // prefetch next row before the reduce
      na = *(const float4*)(rb + (size_t)(s2 + 1) * 512);
      nb = *(const float4*)(rb + (size_t)(s2 + 1) * 512 + 256);
    }
    float p0 = xa.x*wa[0].x + xa.y*wa[0].y + xa.z*wa[0].z + xa.w*wa[0].w
             + xb.x*wb[0].x + xb.y*wb[0].y + xb.z*wb[0].z + xb.w*wb[0].w;
    float p1 = xa.x*wa[1].x + xa.y*wa[1].y + xa.z*wa[1].z + xa.w*wa[1].w
             + xb.x*wb[1].x + xb.y*wb[1].y + xb.z*wb[1].z + xb.w*wb[1].w;
    float p2 = xa.x*wa[2].x + xa.y*wa[2].y + xa.z*wa[2].z + xa.w*wa[2].w
             + xb.x*wb[2].x + xb.y*wb[2].y + xb.z*wb[2].z + xb.w*wb[2].w;
    float p3 = xa.x*wa[3].x + xa.y*wa[3].y + xa.z*wa[3].z + xa.w*wa[3].w
             + xb.x*wb[3].x + xb.y*wb[3].y + xb.z*wb[3].z + xb.w*wb[3].w;
    p0 = wred64(p0); p1 = wred64(p1); p2 = wred64(p2); p3 = wred64(p3);
    if (lane == s2) { r0 = p0; r1 = p1; r2 = p2; r3 = p3; }
    xa = na; xb = nb;
  }

  __syncthreads();   // s_c/s_sn (and later s_qout) visibility

  // ---- Phase B: quantum circuit, lane s handles its sample. ----
  if (lane < WS) {
    constexpr float PI_4 = 0.7853981633974483f;   // theta/2 = tanh(pre)*pi/2 * 0.5
    float st[16];
    #pragma unroll
    for (int i = 0; i < 16; ++i) st[i] = 0.25f;   // H^4 |0000>

    const float pre0 = r0 + bpre[0], pre1 = r1 + bpre[1];
    const float pre2 = r2 + bpre[2], pre3 = r3 + bpre[3];
    float sv, cv;
    __sincosf(tanhf(pre0) * PI_4, &sv, &cv); apply_ry<0>(st, cv, sv);
    __sincosf(tanhf(pre1) * PI_4, &sv, &cv); apply_ry<1>(st, cv, sv);
    __sincosf(tanhf(pre2) * PI_4, &sv, &cv); apply_ry<2>(st, cv, sv);
    __sincosf(tanhf(pre3) * PI_4, &sv, &cv); apply_ry<3>(st, cv, sv);

    #pragma unroll
    for (int k = 0; k < 6; ++k) {
      cnot<0,1>(st); cnot<2,3>(st); cnot<1,2>(st);
      apply_ry<0>(st, s_c[k*4+0], s_sn[k*4+0]);
      apply_ry<1>(st, s_c[k*4+1], s_sn[k*4+1]);
      apply_ry<2>(st, s_c[k*4+2], s_sn[k*4+2]);
      apply_ry<3>(st, s_c[k*4+3], s_sn[k*4+3]);
    }

    float p[16];
    #pragma unroll
    for (int i = 0; i < 16; ++i) p[i] = st[i] * st[i];
    float z0 = 0.f, z1 = 0.f, z2 = 0.f, z3 = 0.f;
    #pragma unroll
    for (int i = 0; i < 16; ++i) {
      z0 += ((i >> 3) & 1) ? -p[i] : p[i];
      z1 += ((i >> 2) & 1) ? -p[i] : p[i];
      z2 += ((i >> 1) & 1) ? -p[i] : p[i];
      z3 += ((i     ) & 1) ? -p[i] : p[i];
    }
    const int sl = wave * WS + lane;
    *(float4*)&s_qout[sl * 4] = make_float4(z0, z1, z2, z3);
  }
  __syncthreads();

  // ---- Phase C: post-GEMV, contiguous 64*200-float span per block. ----
  float* ob = out + (size_t)blockIdx.x * SPB * 200;
  #pragma unroll 2
  for (int idx = tid; idx < SPB * 200; idx += BLOCK) {
    const int sloc = idx / 200;            // magic-div by constant
    const int j = idx - sloc * 200;
    const float4 qo = *(const float4*)&s_qout[sloc * 4];
    const float4 w  = *(const float4*)&s_wpost[j * 4];
    ob[idx] = s_bpost[j] + qo.x * w.x + qo.y * w.y + qo.z * w.z + qo.w * w.w;
  }
}

extern "C" void kernel_launch(void* const* d_in, const int* in_sizes, int n_in,
                              void* d_out, int out_size, void* d_ws, size_t ws_size,
                              hipStream_t stream) {
  const float* in    = (const float*)d_in[0];   // [B,512]
  const float* Wpre  = (const float*)d_in[1];   // [4,512]
  const float* bpre  = (const float*)d_in[2];   // [4]
  const float* qp    = (const float*)d_in[3];   // [24]
  const float* Wpost = (const float*)d_in[4];   // [200,4]
  const float* bpost = (const float*)d_in[5];   // [200]
  float* out = (float*)d_out;                   // [B,200]

  const int B = in_sizes[0] / 512;              // 65536; divisible by SPB
  const int nblk = B / SPB;                     // 1024 blocks
  dqnet_kernel<<<nblk, BLOCK, 0, stream>>>(in, Wpre, bpre, qp, Wpost, bpost, out);
}

// Round 2
// 205.381 us; speedup vs baseline: 1.0829x; 1.0829x over previous
//
#include <hip/hip_runtime.h>

// Fused DressedQuantumNet:
//   pre = in[65536,512] @ W_pre.T[512,4] + b_pre          (memory-bound: 134 MB read)
//   q_in = tanh(pre) * pi/2
//   q_out = 4-qubit circuit (16 real amplitudes, registers)
//   out = q_out @ W_post.T[4,200] + b_post                (52 MB write)
//
// Block=256 (4 waves), wave owns 16 samples, grid = B/64 = 1024.
// Phase A reduction = reduce-scatter: 63 shuffles per wave for all 64
// (sample,q) results (vs 384 for per-result butterflies).

#define BLOCK 256
#define WS 16            // samples per wave
#define SPB 64           // samples per block

typedef float f4 __attribute__((ext_vector_type(4)));

__device__ __forceinline__ f4 ntload4(const float* p) {
  return __builtin_nontemporal_load((const f4*)p);
}

// One reduce-scatter step at xor-mask m. v0 = copy of value with bit==0,
// v1 = value with bit==1. Lane keeps the value whose bit matches (lane&m),
// sends the other; partner's send is exactly my kept value's other half.
__device__ __forceinline__ float rs_step(float v0, float v1, bool hi, int m) {
  const float sd = hi ? v0 : v1;   // send the one I don't keep
  const float kp = hi ? v1 : v0;   // keep the one matching my lane bit
  return kp + __shfl_xor(sd, m, 64);
}

// RY(theta) on qubit Q of a 16-amp state; qubit q lives at bit (3-q).
template<int Q>
__device__ __forceinline__ void apply_ry(float (&st)[16], float c, float s) {
  constexpr int pos = 3 - Q;
  #pragma unroll
  for (int i = 0; i < 16; ++i) {
    if (((i >> pos) & 1) == 0) {
      const int j = i | (1 << pos);
      const float a = st[i], b = st[j];
      st[i] = c * a - s * b;
      st[j] = s * a + c * b;
    }
  }
}

// CNOT: swap target bit where control bit == 1. Pure register renames.
template<int C, int T>
__device__ __forceinline__ void cnot(float (&st)[16]) {
  constexpr int pc = 3 - C, pt = 3 - T;
  #pragma unroll
  for (int i = 0; i < 16; ++i) {
    if ((((i >> pc) & 1) == 1) && (((i >> pt) & 1) == 0)) {
      const int j = i | (1 << pt);
      const float t = st[i]; st[i] = st[j]; st[j] = t;
    }
  }
}

__global__ __launch_bounds__(BLOCK, 4) void dqnet_kernel(
    const float* __restrict__ in, const float* __restrict__ Wpre,
    const float* __restrict__ bpre, const float* __restrict__ qp,
    const float* __restrict__ Wpost, const float* __restrict__ bpost,
    float* __restrict__ out) {
  __shared__ float s_wpost[200 * 4];   // [j][q]
  __shared__ float s_bpost[200];
  __shared__ float s_c[24], s_sn[24];  // cos/sin(qw[k,q]/2)
  __shared__ f4 s_qout[SPB];           // [sample_local] -> (z0,z1,z2,z3)

  const int tid = threadIdx.x;
  const int lane = tid & 63;
  const int wave = tid >> 6;

  // ---- setup: stage W_post/b_post and shared-layer sincos into LDS ----
  if (tid < 200) {
    ((f4*)s_wpost)[tid] = ((const f4*)Wpost)[tid];
    s_bpost[tid] = bpost[tid];
  } else if (tid < 224) {
    const int k = tid - 200;
    const float a = qp[k] * 0.5f;
    s_c[k] = __cosf(a);
    s_sn[k] = __sinf(a);
  }

  // Per-lane W_pre fragment: features [lane*4, lane*4+4) and +256.
  f4 wa[4], wb[4];
  #pragma unroll
  for (int q = 0; q < 4; ++q) {
    wa[q] = *(const f4*)(Wpre + q * 512 + lane * 4);
    wb[q] = *(const f4*)(Wpre + q * 512 + 256 + lane * 4);
  }

  // ---- Phase A: pre-GEMV, coalesced full-row loads, per-lane partials ----
  const int tile = blockIdx.x * SPB + wave * WS;
  const float* rb = in + (size_t)tile * 512 + lane * 4;

  const bool b1 = (lane & 1) != 0;
  const bool b2 = (lane & 2) != 0;

  float part[WS];                       // per-sample quad-cluster partials
  f4 xa = ntload4(rb);
  f4 xb = ntload4(rb + 256);
  #pragma unroll
  for (int s = 0; s < WS; ++s) {
    f4 na = xa, nb = xb;
    if (s + 1 < WS) {                   // prefetch next row
      na = ntload4(rb + (size_t)(s + 1) * 512);
      nb = ntload4(rb + (size_t)(s + 1) * 512 + 256);
    }
    float p0 = xa.x*wa[0].x + xa.y*wa[0].y + xa.z*wa[0].z + xa.w*wa[0].w
             + xb.x*wb[0].x + xb.y*wb[0].y + xb.z*wb[0].z + xb.w*wb[0].w;
    float p1 = xa.x*wa[1].x + xa.y*wa[1].y + xa.z*wa[1].z + xa.w*wa[1].w
             + xb.x*wb[1].x + xb.y*wb[1].y + xb.z*wb[1].z + xb.w*wb[1].w;
    float p2 = xa.x*wa[2].x + xa.y*wa[2].y + xa.z*wa[2].z + xa.w*wa[2].w
             + xb.x*wb[2].x + xb.y*wb[2].y + xb.z*wb[2].z + xb.w*wb[2].w;
    float p3 = xa.x*wa[3].x + xa.y*wa[3].y + xa.z*wa[3].z + xa.w*wa[3].w
             + xb.x*wb[3].x + xb.y*wb[3].y + xb.z*wb[3].z + xb.w*wb[3].w;
    // quad reduce: q-bit0 <-> lane bit0, q-bit1 <-> lane bit1 (3 shuffles)
    const float a01 = rs_step(p0, p1, b1, 1);
    const float a23 = rs_step(p2, p3, b1, 1);
    part[s] = rs_step(a01, a23, b2, 2);   // q = lane&3, summed over 4-lane cluster
    xa = na; xb = nb;
  }

  // cluster reduce-scatter: sample-bit j <-> lane-bit (j+2); 15 shuffles
  const bool b4  = (lane & 4)  != 0;
  const bool b8  = (lane & 8)  != 0;
  const bool b16 = (lane & 16) != 0;
  const bool b32 = (lane & 32) != 0;
  float a8[8], a4[4], a2[2];
  #pragma unroll
  for (int u = 0; u < 8; ++u) a8[u] = rs_step(part[2*u], part[2*u+1], b4, 4);
  #pragma unroll
  for (int u = 0; u < 4; ++u) a4[u] = rs_step(a8[2*u], a8[2*u+1], b8, 8);
  #pragma unroll
  for (int u = 0; u < 2; ++u) a2[u] = rs_step(a4[2*u], a4[2*u+1], b16, 16);
  const float r = rs_step(a2[0], a2[1], b32, 32);
  // lane l now holds pre-dot for sample (l>>2), output (l&3)

  // redistribute: lane s (s<16) gathers its 4 outputs (all lanes execute)
  const float g0 = __shfl(r, (lane << 2) | 0, 64);
  const float g1 = __shfl(r, (lane << 2) | 1, 64);
  const float g2 = __shfl(r, (lane << 2) | 2, 64);
  const float g3 = __shfl(r, (lane << 2) | 3, 64);

  __syncthreads();   // s_c/s_sn ready; also orders s_qout below

  // ---- Phase B: quantum circuit, lane s handles its sample ----
  if (lane < WS) {
    constexpr float PI_4 = 0.7853981633974483f;   // theta/2 = tanh*pi/2*0.5
    float st[16];
    #pragma unroll
    for (int i = 0; i < 16; ++i) st[i] = 0.25f;   // H^4 |0000>

    float sv, cv;
    __sincosf(tanhf(g0 + bpre[0]) * PI_4, &sv, &cv); apply_ry<0>(st, cv, sv);
    __sincosf(tanhf(g1 + bpre[1]) * PI_4, &sv, &cv); apply_ry<1>(st, cv, sv);
    __sincosf(tanhf(g2 + bpre[2]) * PI_4, &sv, &cv); apply_ry<2>(st, cv, sv);
    __sincosf(tanhf(g3 + bpre[3]) * PI_4, &sv, &cv); apply_ry<3>(st, cv, sv);

    #pragma unroll
    for (int k = 0; k < 6; ++k) {
      cnot<0,1>(st); cnot<2,3>(st); cnot<1,2>(st);
      apply_ry<0>(st, s_c[k*4+0], s_sn[k*4+0]);
      apply_ry<1>(st, s_c[k*4+1], s_sn[k*4+1]);
      apply_ry<2>(st, s_c[k*4+2], s_sn[k*4+2]);
      apply_ry<3>(st, s_c[k*4+3], s_sn[k*4+3]);
    }

    float p[16];
    #pragma unroll
    for (int i = 0; i < 16; ++i) p[i] = st[i] * st[i];
    float z0 = 0.f, z1 = 0.f, z2 = 0.f, z3 = 0.f;
    #pragma unroll
    for (int i = 0; i < 16; ++i) {
      z0 += ((i >> 3) & 1) ? -p[i] : p[i];
      z1 += ((i >> 2) & 1) ? -p[i] : p[i];
      z2 += ((i >> 1) & 1) ? -p[i] : p[i];
      z3 += ((i     ) & 1) ? -p[i] : p[i];
    }
    f4 z; z.x = z0; z.y = z1; z.z = z2; z.w = z3;
    s_qout[wave * WS + lane] = z;
  }
  __syncthreads();

  // ---- Phase C: post-GEMV, float4 nontemporal stores (3200 f4/block) ----
  float* ob = out + (size_t)blockIdx.x * (SPB * 200);
  #pragma unroll
  for (int i = 0; i < 13; ++i) {
    const int idx4 = tid + i * BLOCK;
    if (idx4 < 3200) {
      const int sloc = idx4 / 50;          // magic-div by constant
      const int j4 = idx4 - sloc * 50;     // float4 index within the row
      const f4 qo = s_qout[sloc];
      const f4* wrow = (const f4*)&s_wpost[j4 * 16];
      const float* br = &s_bpost[j4 * 4];
      f4 o;
      o.x = br[0] + wrow[0].x*qo.x + wrow[0].y*qo.y + wrow[0].z*qo.z + wrow[0].w*qo.w;
      o.y = br[1] + wrow[1].x*qo.x + wrow[1].y*qo.y + wrow[1].z*qo.z + wrow[1].w*qo.w;
      o.z = br[2] + wrow[2].x*qo.x + wrow[2].y*qo.y + wrow[2].z*qo.z + wrow[2].w*qo.w;
      o.w = br[3] + wrow[3].x*qo.x + wrow[3].y*qo.y + wrow[3].z*qo.z + wrow[3].w*qo.w;
      __builtin_nontemporal_store(o, (f4*)(ob + (size_t)idx4 * 4));
    }
  }
}

extern "C" void kernel_launch(void* const* d_in, const int* in_sizes, int n_in,
                              void* d_out, int out_size, void* d_ws, size_t ws_size,
                              hipStream_t stream) {
  const float* in    = (const float*)d_in[0];   // [B,512]
  const float* Wpre  = (const float*)d_in[1];   // [4,512]
  const float* bpre  = (const float*)d_in[2];   // [4]
  const float* qp    = (const float*)d_in[3];   // [24]
  const float* Wpost = (const float*)d_in[4];   // [200,4]
  const float* bpost = (const float*)d_in[5];   // [200]
  float* out = (float*)d_out;                   // [B,200]

  const int B = in_sizes[0] / 512;              // 65536
  const int nblk = B / SPB;                     // 1024
  dqnet_kernel<<<nblk, BLOCK, 0, stream>>>(in, Wpre, bpre, qp, Wpost, bpost, out);
}

// Round 3
// 204.600 us; speedup vs baseline: 1.0871x; 1.0038x over previous
//
#include <hip/hip_runtime.h>

// Fused DressedQuantumNet:
//   pre = in[65536,512] @ W_pre.T[512,4] + b_pre          (memory-bound: 134 MB read)
//   q_in = tanh(pre) * pi/2
//   q_out = 4-qubit circuit (16 real amplitudes, registers)
//   out = q_out @ W_post.T[4,200] + b_post                (52 MB write)
//
// Block=256 (4 waves), wave owns 16 samples, grid = B/64 = 1024.
// Phase A: reduce-scatter (63 shuffles/wave for all 64 results) + depth-2
// row prefetch ring (4 loads in flight per wave for latency hiding).

#define BLOCK 256
#define WS 16            // samples per wave
#define SPB 64           // samples per block

typedef float f4 __attribute__((ext_vector_type(4)));

__device__ __forceinline__ f4 ntload4(const float* p) {
  return __builtin_nontemporal_load((const f4*)p);
}

// One reduce-scatter step at xor-mask m. v0 = copy with bit==0, v1 = bit==1.
// Lane keeps the copy matching (lane&m), sends the other.
__device__ __forceinline__ float rs_step(float v0, float v1, bool hi, int m) {
  const float sd = hi ? v0 : v1;
  const float kp = hi ? v1 : v0;
  return kp + __shfl_xor(sd, m, 64);
}

// RY(theta) on qubit Q of a 16-amp state; qubit q lives at bit (3-q).
template<int Q>
__device__ __forceinline__ void apply_ry(float (&st)[16], float c, float s) {
  constexpr int pos = 3 - Q;
  #pragma unroll
  for (int i = 0; i < 16; ++i) {
    if (((i >> pos) & 1) == 0) {
      const int j = i | (1 << pos);
      const float a = st[i], b = st[j];
      st[i] = c * a - s * b;
      st[j] = s * a + c * b;
    }
  }
}

// CNOT: swap target bit where control bit == 1. Pure register renames.
template<int C, int T>
__device__ __forceinline__ void cnot(float (&st)[16]) {
  constexpr int pc = 3 - C, pt = 3 - T;
  #pragma unroll
  for (int i = 0; i < 16; ++i) {
    if ((((i >> pc) & 1) == 1) && (((i >> pt) & 1) == 0)) {
      const int j = i | (1 << pt);
      const float t = st[i]; st[i] = st[j]; st[j] = t;
    }
  }
}

__global__ __launch_bounds__(BLOCK, 4) void dqnet_kernel(
    const float* __restrict__ in, const float* __restrict__ Wpre,
    const float* __restrict__ bpre, const float* __restrict__ qp,
    const float* __restrict__ Wpost, const float* __restrict__ bpost,
    float* __restrict__ out) {
  __shared__ float s_wpost[200 * 4];   // [j][q]
  __shared__ float s_bpost[200];
  __shared__ float s_c[24], s_sn[24];  // cos/sin(qw[k,q]/2)
  __shared__ f4 s_qout[SPB];           // [sample_local] -> (z0,z1,z2,z3)

  const int tid = threadIdx.x;
  const int lane = tid & 63;
  const int wave = tid >> 6;

  // ---- setup: stage W_post/b_post and shared-layer sincos into LDS ----
  if (tid < 200) {
    ((f4*)s_wpost)[tid] = ((const f4*)Wpost)[tid];
    s_bpost[tid] = bpost[tid];
  } else if (tid < 224) {
    const int k = tid - 200;
    const float a = qp[k] * 0.5f;
    s_c[k] = __cosf(a);
    s_sn[k] = __sinf(a);
  }

  // Per-lane W_pre fragment: features [lane*4, lane*4+4) and +256.
  f4 wa[4], wb[4];
  #pragma unroll
  for (int q = 0; q < 4; ++q) {
    wa[q] = *(const f4*)(Wpre + q * 512 + lane * 4);
    wb[q] = *(const f4*)(Wpre + q * 512 + 256 + lane * 4);
  }

  // ---- Phase A: pre-GEMV, depth-2 prefetch ring, per-lane partials ----
  const int tile = blockIdx.x * SPB + wave * WS;
  const float* rb = in + (size_t)tile * 512 + lane * 4;

  const bool b1 = (lane & 1) != 0;
  const bool b2 = (lane & 2) != 0;

  float part[WS];
  f4 pxa[2], pxb[2];
  pxa[0] = ntload4(rb);        pxb[0] = ntload4(rb + 256);
  pxa[1] = ntload4(rb + 512);  pxb[1] = ntload4(rb + 512 + 256);
  #pragma unroll
  for (int s = 0; s < WS; ++s) {
    const f4 xa = pxa[s & 1], xb = pxb[s & 1];
    if (s + 2 < WS) {                 // refill ring slot two ahead
      pxa[s & 1] = ntload4(rb + (size_t)(s + 2) * 512);
      pxb[s & 1] = ntload4(rb + (size_t)(s + 2) * 512 + 256);
    }
    float p0 = xa.x*wa[0].x + xa.y*wa[0].y + xa.z*wa[0].z + xa.w*wa[0].w
             + xb.x*wb[0].x + xb.y*wb[0].y + xb.z*wb[0].z + xb.w*wb[0].w;
    float p1 = xa.x*wa[1].x + xa.y*wa[1].y + xa.z*wa[1].z + xa.w*wa[1].w
             + xb.x*wb[1].x + xb.y*wb[1].y + xb.z*wb[1].z + xb.w*wb[1].w;
    float p2 = xa.x*wa[2].x + xa.y*wa[2].y + xa.z*wa[2].z + xa.w*wa[2].w
             + xb.x*wb[2].x + xb.y*wb[2].y + xb.z*wb[2].z + xb.w*wb[2].w;
    float p3 = xa.x*wa[3].x + xa.y*wa[3].y + xa.z*wa[3].z + xa.w*wa[3].w
             + xb.x*wb[3].x + xb.y*wb[3].y + xb.z*wb[3].z + xb.w*wb[3].w;
    // quad reduce: q-bit0 <-> lane bit0, q-bit1 <-> lane bit1 (3 shuffles)
    const float a01 = rs_step(p0, p1, b1, 1);
    const float a23 = rs_step(p2, p3, b1, 1);
    part[s] = rs_step(a01, a23, b2, 2);   // q = lane&3, summed over quad
  }

  // cluster reduce-scatter: sample-bit j <-> lane-bit (j+2); 15 shuffles
  const bool b4  = (lane & 4)  != 0;
  const bool b8  = (lane & 8)  != 0;
  const bool b16 = (lane & 16) != 0;
  const bool b32 = (lane & 32) != 0;
  float a8[8], a4[4], a2[2];
  #pragma unroll
  for (int u = 0; u < 8; ++u) a8[u] = rs_step(part[2*u], part[2*u+1], b4, 4);
  #pragma unroll
  for (int u = 0; u < 4; ++u) a4[u] = rs_step(a8[2*u], a8[2*u+1], b8, 8);
  #pragma unroll
  for (int u = 0; u < 2; ++u) a2[u] = rs_step(a4[2*u], a4[2*u+1], b16, 16);
  const float r = rs_step(a2[0], a2[1], b32, 32);
  // lane l holds pre-dot for sample (l>>2), output (l&3)

  // redistribute: lane s (s<16) gathers its 4 outputs (all lanes execute)
  const float g0 = __shfl(r, (lane << 2) | 0, 64);
  const float g1 = __shfl(r, (lane << 2) | 1, 64);
  const float g2 = __shfl(r, (lane << 2) | 2, 64);
  const float g3 = __shfl(r, (lane << 2) | 3, 64);

  __syncthreads();   // s_c/s_sn ready; also orders s_qout below

  // ---- Phase B: quantum circuit, lane s handles its sample ----
  if (lane < WS) {
    constexpr float PI_4 = 0.7853981633974483f;   // theta/2 = tanh*pi/2*0.5
    float st[16];
    #pragma unroll
    for (int i = 0; i < 16; ++i) st[i] = 0.25f;   // H^4 |0000>

    float sv, cv;
    __sincosf(tanhf(g0 + bpre[0]) * PI_4, &sv, &cv); apply_ry<0>(st, cv, sv);
    __sincosf(tanhf(g1 + bpre[1]) * PI_4, &sv, &cv); apply_ry<1>(st, cv, sv);
    __sincosf(tanhf(g2 + bpre[2]) * PI_4, &sv, &cv); apply_ry<2>(st, cv, sv);
    __sincosf(tanhf(g3 + bpre[3]) * PI_4, &sv, &cv); apply_ry<3>(st, cv, sv);

    #pragma unroll
    for (int k = 0; k < 6; ++k) {
      cnot<0,1>(st); cnot<2,3>(st); cnot<1,2>(st);
      apply_ry<0>(st, s_c[k*4+0], s_sn[k*4+0]);
      apply_ry<1>(st, s_c[k*4+1], s_sn[k*4+1]);
      apply_ry<2>(st, s_c[k*4+2], s_sn[k*4+2]);
      apply_ry<3>(st, s_c[k*4+3], s_sn[k*4+3]);
    }

    float p[16];
    #pragma unroll
    for (int i = 0; i < 16; ++i) p[i] = st[i] * st[i];
    float z0 = 0.f, z1 = 0.f, z2 = 0.f, z3 = 0.f;
    #pragma unroll
    for (int i = 0; i < 16; ++i) {
      z0 += ((i >> 3) & 1) ? -p[i] : p[i];
      z1 += ((i >> 2) & 1) ? -p[i] : p[i];
      z2 += ((i >> 1) & 1) ? -p[i] : p[i];
      z3 += ((i     ) & 1) ? -p[i] : p[i];
    }
    f4 z; z.x = z0; z.y = z1; z.z = z2; z.w = z3;
    s_qout[wave * WS + lane] = z;
  }
  __syncthreads();

  // ---- Phase C: post-GEMV, float4 nontemporal stores (3200 f4/block) ----
  float* ob = out + (size_t)blockIdx.x * (SPB * 200);
  #pragma unroll
  for (int i = 0; i < 13; ++i) {
    const int idx4 = tid + i * BLOCK;
    if (idx4 < 3200) {
      const int sloc = idx4 / 50;          // magic-div by constant
      const int j4 = idx4 - sloc * 50;     // float4 index within the row
      const f4 qo = s_qout[sloc];
      const f4* wrow = (const f4*)&s_wpost[j4 * 16];
      const float* br = &s_bpost[j4 * 4];
      f4 o;
      o.x = br[0] + wrow[0].x*qo.x + wrow[0].y*qo.y + wrow[0].z*qo.z + wrow[0].w*qo.w;
      o.y = br[1] + wrow[1].x*qo.x + wrow[1].y*qo.y + wrow[1].z*qo.z + wrow[1].w*qo.w;
      o.z = br[2] + wrow[2].x*qo.x + wrow[2].y*qo.y + wrow[2].z*qo.z + wrow[2].w*qo.w;
      o.w = br[3] + wrow[3].x*qo.x + wrow[3].y*qo.y + wrow[3].z*qo.z + wrow[3].w*qo.w;
      __builtin_nontemporal_store(o, (f4*)(ob + (size_t)idx4 * 4));
    }
  }
}

extern "C" void kernel_launch(void* const* d_in, const int* in_sizes, int n_in,
                              void* d_out, int out_size, void* d_ws, size_t ws_size,
                              hipStream_t stream) {
  const float* in    = (const float*)d_in[0];   // [B,512]
  const float* Wpre  = (const float*)d_in[1];   // [4,512]
  const float* bpre  = (const float*)d_in[2];   // [4]
  const float* qp    = (const float*)d_in[3];   // [24]
  const float* Wpost = (const float*)d_in[4];   // [200,4]
  const float* bpost = (const float*)d_in[5];   // [200]
  float* out = (float*)d_out;                   // [B,200]

  const int B = in_sizes[0] / 512;              // 65536
  const int nblk = B / SPB;                     // 1024
  dqnet_kernel<<<nblk, BLOCK, 0, stream>>>(in, Wpre, bpre, qp, Wpost, bpost, out);
}